// Round 20
// baseline (50.362 us; speedup 1.0000x reference)
//
#include <hip/hip_runtime.h>
#include <hip/hip_bf16.h>

#define H_IN 4096
#define W_IN 4096
#define KH 15
#define KW 15
#define OH (H_IN - KH + 1)   // 4082
#define OW (W_IN - KW + 1)   // 4082

#define BM 64                // output rows per block (4 waves x 16)
#define BN 128               // output cols per block (NJ=8 j-frags)
#define NJ (BN / 16)         // 8
#define SROWS (BM + KH - 1)  // 78 staged rows
#define SGROW 19             // 16B granules per row (152 bf16 cols; 144 used)
#define SSTR  152            // row stride in ushort = 19 granules (r11-proven 2-way banking)
#define DMAGR 1536           // granules DMA'd per tile (6 full 256-thread iters >= 78*19=1482)

#define XBF_ELEMS ((size_t)H_IN * W_IN)
#define XBF_PAD   ((XBF_ELEMS + 4096) * 2)          // bf16 X + overrun pad
#define WS_NEED   (XBF_PAD + (size_t)KH * 64 * 8 * 2)

typedef __attribute__((ext_vector_type(8))) short short8;   // MFMA A/B frag
typedef __attribute__((ext_vector_type(4))) float f32x4;    // MFMA C/D frag

__device__ __forceinline__ ushort f2bf(float f) {
    __hip_bfloat16 h = __float2bfloat16(f);
    return __builtin_bit_cast(ushort, h);
}
__device__ __forceinline__ uint32_t pk2(float a, float b) {
    return (uint32_t)f2bf(a) | ((uint32_t)f2bf(b) << 16);
}
__device__ __forceinline__ void gload_lds16(const void* g, void* l) {
    __builtin_amdgcn_global_load_lds(
        (const __attribute__((address_space(1))) void*)g,
        (__attribute__((address_space(3))) void*)l, 16, 0, 0);
}

// ---- pass 1: X fp32 -> bf16 (streaming, BW-bound) ----
__global__ __launch_bounds__(256, 8)
void convert_bf16(const float* __restrict__ X, ushort* __restrict__ Xb)
{
    size_t i8 = ((size_t)blockIdx.x * 256 + threadIdx.x) * 8;
    float4 a = *reinterpret_cast<const float4*>(X + i8);
    float4 b = *reinterpret_cast<const float4*>(X + i8 + 4);
    uint4 pk;
    pk.x = pk2(a.x, a.y); pk.y = pk2(a.z, a.w);
    pk.z = pk2(b.x, b.y); pk.w = pk2(b.z, b.w);
    *reinterpret_cast<uint4*>(Xb + i8) = pk;
}

// ---- prep: banded Toeplitz weight frags -> workspace ----
// B[k][j] = w[kh][k-j]; lane l holds B[8*(l>>4)+u][l&15], u=0..7
__global__ __launch_bounds__(256)
void build_wfrags(const float* __restrict__ Wt, ushort* __restrict__ Bw)
{
    int idx = blockIdx.x * 256 + threadIdx.x;
    if (idx < KH * 64) {
        int kh = idx >> 6, l = idx & 63;
        int j = l & 15, k0 = (l >> 4) * 8;
        union { ushort u[8]; uint4 v; } t;
#pragma unroll
        for (int u = 0; u < 8; ++u) {
            int kw = k0 + u - j;
            t.u[u] = f2bf((kw >= 0 && kw < KW) ? Wt[kh * KW + kw] : 0.0f);
        }
        *reinterpret_cast<uint4*>(&Bw[idx * 8]) = t.v;
    }
}

// ---- pass 2: main MFMA kernel, stage = 6 global_load_lds DMAs ----
__global__ __launch_bounds__(256, 4)
void conv2d_mfma_dma(const ushort* __restrict__ Xb,
                     const ushort* __restrict__ Bw,
                     const float* __restrict__ Bias,
                     float* __restrict__ Out)
{
    __shared__ ushort s_x[DMAGR * 8];        // 24576 B (1482 used + slack)

    const int tid = threadIdx.x;
    const int l = tid & 63;
    const int w = tid >> 6;
    const int ox0 = blockIdx.x * BN;
    const int oy0 = blockIdx.y * BM;

    // ---- stage: per-lane global src, linear LDS dest (HW: base + lane*16) ----
#pragma unroll
    for (int k = 0; k < 6; ++k) {
        int i = tid + 256 * k;               // granule index, < 1536
        int r = i / SGROW;                   // 0..80 (rows 78+ staged harmlessly)
        int g = i - r * SGROW;
        int gy = min(oy0 + r, H_IN - 1);
        const ushort* src = Xb + (size_t)gy * W_IN + (ox0 + g * 8);
        gload_lds16(src, (char*)s_x + (k * 4 + w) * 1024);   // wave-uniform base
    }
    __syncthreads();     // compiler drains vmcnt (DMAs) before barrier

    // ---- B-frags hoist (no stage regs now -> 60 VGPR fits) ----
    const ushort* const bbase = Bw + l * 8;
    short8 bfr[KH];
#pragma unroll
    for (int kh = 0; kh < KH; ++kh)
        bfr[kh] = *reinterpret_cast<const short8*>(bbase + kh * 64 * 8);
    __builtin_amdgcn_sched_barrier(0);

    // ---- compute: per kh {8 A-reads, 8 MFMAs} (r11-verbatim geometry) ----
    const ushort* const abase = &s_x[(w * 16 + (l & 15)) * SSTR + (l >> 4) * 8];

    f32x4 acc[NJ];
#pragma unroll
    for (int j = 0; j < NJ; ++j) acc[j] = (f32x4){0.f, 0.f, 0.f, 0.f};

#pragma unroll
    for (int kh = 0; kh < KH; ++kh) {
        const ushort* arow = abase + kh * SSTR;
#pragma unroll
        for (int j = 0; j < NJ; ++j) {
            short8 a = *reinterpret_cast<const short8*>(arow + j * 16);
            acc[j] = __builtin_amdgcn_mfma_f32_16x16x32_bf16(a, bfr[kh], acc[j], 0, 0, 0);
        }
    }

    // ---- store: C/D layout col=lane&15, row=(lane>>4)*4+r ----
    const float b = Bias[0];
    const int orow0 = oy0 + w * 16 + (l >> 4) * 4;
    const int ocol  = ox0 + (l & 15);
    if (oy0 + BM <= OH && ox0 + BN <= OW) {
        float* op0 = &Out[(size_t)orow0 * OW + ocol];
#pragma unroll
        for (int j = 0; j < NJ; ++j) {
#pragma unroll
            for (int r = 0; r < 4; ++r)
                op0[(size_t)r * OW + j * 16] = acc[j][r] + b;
        }
    } else {
#pragma unroll
        for (int j = 0; j < NJ; ++j) {
            int oc = ocol + j * 16;
            if (oc < OW) {
#pragma unroll
                for (int r = 0; r < 4; ++r) {
                    int orow = orow0 + r;
                    if (orow < OH)
                        Out[(size_t)orow * OW + oc] = acc[j][r] + b;
                }
            }
        }
    }
}

// ---- fallback (ws too small): self-contained, LDS weight frags + batched stage ----
__global__ __launch_bounds__(256, 4)
void conv2d_fallback(const float* __restrict__ X,
                     const float* __restrict__ Wt,
                     const float* __restrict__ Bias,
                     float* __restrict__ Out)
{
    __shared__ ushort s_w[KH * 64 * 8];
    __shared__ ushort s_x[SROWS * SSTR];

    const int tid = threadIdx.x;
    const int l = tid & 63;
    const int w = tid >> 6;
    const int ox0 = blockIdx.x * BN;
    const int oy0 = blockIdx.y * BM;
    const bool xint = (ox0 + 144 <= W_IN);

    for (int idx = tid; idx < KH * 64; idx += 256) {
        int kh = idx >> 6, ll = idx & 63;
        int j = ll & 15, k0 = (ll >> 4) * 8;
        union { ushort u[8]; uint4 q; } t;
#pragma unroll
        for (int u = 0; u < 8; ++u) {
            int kw = k0 + u - j;
            t.u[u] = f2bf((kw >= 0 && kw < KW) ? Wt[kh * KW + kw] : 0.0f);
        }
        *reinterpret_cast<uint4*>(&s_w[idx * 8]) = t.q;
    }

    for (int i = tid; i < SROWS * 36; i += 256) {
        int r = i / 36, c4 = i % 36;
        int gy = min(oy0 + r, H_IN - 1);
        const float* rp = X + (size_t)gy * W_IN;
        int gx = ox0 + c4 * 4;
        float4 v;
        if (xint) v = *reinterpret_cast<const float4*>(rp + gx);
        else {
            v.x = rp[min(gx + 0, W_IN - 1)];
            v.y = rp[min(gx + 1, W_IN - 1)];
            v.z = rp[min(gx + 2, W_IN - 1)];
            v.w = rp[min(gx + 3, W_IN - 1)];
        }
        uint2 pk; pk.x = pk2(v.x, v.y); pk.y = pk2(v.z, v.w);
        *reinterpret_cast<uint2*>(&s_x[r * SSTR + c4 * 4]) = pk;
    }
    __syncthreads();

    const ushort* const abase = &s_x[(w * 16 + (l & 15)) * SSTR + (l >> 4) * 8];
    const ushort* const bbase = &s_w[l * 8];
    f32x4 acc[NJ];
#pragma unroll
    for (int j = 0; j < NJ; ++j) acc[j] = (f32x4){0.f, 0.f, 0.f, 0.f};
#pragma unroll
    for (int kh = 0; kh < KH; ++kh) {
        short8 bf = *reinterpret_cast<const short8*>(bbase + kh * 64 * 8);
        const ushort* arow = abase + kh * SSTR;
#pragma unroll
        for (int j = 0; j < NJ; ++j) {
            short8 a = *reinterpret_cast<const short8*>(arow + j * 16);
            acc[j] = __builtin_amdgcn_mfma_f32_16x16x32_bf16(a, bf, acc[j], 0, 0, 0);
        }
    }
    const float b = Bias[0];
    const int orow0 = oy0 + w * 16 + (l >> 4) * 4;
    const int ocol  = ox0 + (l & 15);
#pragma unroll
    for (int j = 0; j < NJ; ++j) {
        int oc = ocol + j * 16;
        if (oc < OW) {
#pragma unroll
            for (int r = 0; r < 4; ++r) {
                int orow = orow0 + r;
                if (orow < OH) Out[(size_t)orow * OW + oc] = acc[j][r] + b;
            }
        }
    }
}

extern "C" void kernel_launch(void* const* d_in, const int* in_sizes, int n_in,
                              void* d_out, int out_size, void* d_ws, size_t ws_size,
                              hipStream_t stream)
{
    const float* X    = (const float*)d_in[0];
    const float* Wt   = (const float*)d_in[1];
    const float* Bias = (const float*)d_in[2];
    float* Out        = (float*)d_out;

    if (ws_size >= WS_NEED) {
        ushort* Xb = (ushort*)d_ws;
        ushort* Bw = (ushort*)((char*)d_ws + XBF_PAD);

        hipLaunchKernelGGL(convert_bf16, dim3(XBF_ELEMS / 8 / 256), dim3(256), 0, stream,
                           X, Xb);                                  // 8192 blocks
        hipLaunchKernelGGL(build_wfrags, dim3((KH * 64 + 255) / 256), dim3(256), 0, stream,
                           Wt, Bw);
        dim3 grid((OW + BN - 1) / BN, (OH + BM - 1) / BM);          // 32 x 64
        hipLaunchKernelGGL(conv2d_mfma_dma, grid, dim3(256), 0, stream,
                           Xb, Bw, Bias, Out);
    } else {
        dim3 grid((OW + BN - 1) / BN, (OH + BM - 1) / BM);
        hipLaunchKernelGGL(conv2d_fallback, grid, dim3(256), 0, stream,
                           X, Wt, Bias, Out);
    }
}